// Round 11
// baseline (246.687 us; speedup 1.0000x reference)
//
#include <hip/hip_runtime.h>
#include <hip/hip_fp16.h>

// FullAttention fwd: BH=32, T=2048, D=128, fp32 in/out, key_padding_mask (True=masked).
// R10: 2 blocks/CU. QB=128 (8 waves x 16 q), grid (32,16) = 512 blocks, LDS 66.5KB x2
// co-resident -> one block's barrier/staging drain overlaps the other's compute.
// FP16 single-pass MFMA (16x16x32_f16). Double-buffered LDS, ONE barrier/iter.
// Swapped QK^T (mfma(K,Q)) => softmax lane-local; P in-register feeds PV A-operand;
// V^T sigma layout gives one b128 read per PV B-frag. T13 defer-max (THR=8) skips
// O-rescale when running max doesn't grow. exp2-folded scale (log2e premultiplied).

#define BHN  32
#define TSEQ 2048
#define DDIM 128
#define QB   128   // q rows per block
#define KB   64    // kv rows per tile
#define NKT  (TSEQ / KB)

typedef __attribute__((ext_vector_type(4))) float    f32x4;
typedef __attribute__((ext_vector_type(8))) _Float16 f16x8;
typedef __attribute__((ext_vector_type(4))) _Float16 f16x4;

// K byte addr (row-major [64][128] f16, m214 XOR swizzle)
__device__ __forceinline__ unsigned kaddr(int row, int d) {
    return ((unsigned)(row * 256 + d * 2)) ^ ((unsigned)(row & 7) << 4);
}
// V^T byte addr: (d, kvp) with 16B-granule XOR swizzle (preserves b64/b128 alignment)
__device__ __forceinline__ unsigned vaddr(int d, int kvp) {
    return ((unsigned)(d * 128 + kvp * 2)) ^ (((unsigned)((d ^ (d >> 3)) & 7)) << 4);
}

__global__ __launch_bounds__(512, 2)
void attn_fwd(const float* __restrict__ Qg, const float* __restrict__ Kg,
              const float* __restrict__ Vg, const unsigned char* __restrict__ Mg,
              float* __restrict__ Og)
{
    __shared__ __align__(16) unsigned short Kh[2][KB * DDIM]; // 2x16KB f16, XOR-swizzled
    __shared__ __align__(16) unsigned short Vt[2][DDIM * KB]; // 2x16KB f16 (d, sigma(kv))
    __shared__ float biasLds[2][KB];
    __shared__ int mflag;

    const int tid  = threadIdx.x;
    const int lane = tid & 63;
    const int wave = tid >> 6;
    const int q16  = lane & 15;
    const int hi   = lane >> 4;

    const int bh    = blockIdx.x;
    const int qbase = blockIdx.y * QB + wave * 16;

    // 1/sqrt(128) * log2(e): softmax computed in exp2 units
    const float scale = 0.088388347648318447f * 1.4426950408889634f;

    const float* Qp = Qg + ((size_t)bh * TSEQ + qbase) * DDIM;
    const float* Kp = Kg + (size_t)bh * TSEQ * DDIM;
    const float* Vp = Vg + (size_t)bh * TSEQ * DDIM;

    // ---- mask layout detection (probe first 2KB; valid under both layouts) ----
    if (tid == 0) mflag = 0;
    __syncthreads();
    {
        int f = 0;
#pragma unroll
        for (int j = 0; j < 4; ++j) {
            const int idx = tid * 4 + j;
            if ((idx & 3) != 0 && Mg[idx] != 0) f = 1;
        }
        if (f) atomicOr(&mflag, 1);
    }
    __syncthreads();
    const int isByte = mflag;   // block-uniform

    // ---- Q fragments (fp16): lane holds Q[q16][32c+8hi+i]*scale ----
    f16x8 qf[4];
    {
        const float* qrow = Qp + (size_t)q16 * DDIM;
#pragma unroll
        for (int c = 0; c < 4; ++c) {
            const int d0 = 32 * c + 8 * hi;
            f32x4 a = *reinterpret_cast<const f32x4*>(qrow + d0);
            f32x4 b = *reinterpret_cast<const f32x4*>(qrow + d0 + 4);
            f16x8 f;
#pragma unroll
            for (int i = 0; i < 8; ++i)
                f[i] = (_Float16)((i < 4 ? a[i] : b[i - 4]) * scale);
            qf[c] = f;
        }
    }

    f32x4 o[8];
#pragma unroll
    for (int db = 0; db < 8; ++db)
        o[db] = (f32x4){0.f, 0.f, 0.f, 0.f};
    float mrun = -1e30f;
    float lrun = 0.f;

    // ---- staging assignment: thread owns kv-quad rb..rb+3 at d = sd..sd+3 ----
    const int sd   = (tid & 31) * 4;
    const int qrw  = (((tid >> 5) & 1) << 2) | ((tid >> 6) & 3) | (((tid >> 8) & 1) << 3);
    const int rb   = qrw * 4;
    // sigma base of the quad: sigma(4m+r) = kvpb + r
    const int kvpb = (((qrw >> 2) & 1) << 2) | ((qrw & 3) << 3) | (((qrw >> 3) & 1) << 5);

    f32x4 kreg[4], vreg[4];
    int mreg = 0;

#define LOAD_TILE(kv0)                                                              \
    {                                                                               \
        _Pragma("unroll")                                                           \
        for (int r = 0; r < 4; ++r) {                                               \
            kreg[r] = *reinterpret_cast<const f32x4*>(Kp + (size_t)((kv0) + rb + r) * DDIM + sd); \
            vreg[r] = *reinterpret_cast<const f32x4*>(Vp + (size_t)((kv0) + rb + r) * DDIM + sd); \
        }                                                                           \
        if (tid < KB) {                                                             \
            const size_t mi = (size_t)bh * TSEQ + (kv0) + tid;                      \
            mreg = isByte ? (int)Mg[mi] : ((const int*)Mg)[mi];                     \
        }                                                                           \
    }

#define STORE_TILE(b)                                                               \
    {                                                                               \
        if (tid < KB) biasLds[b][tid] = mreg ? -1e30f : 0.0f;                       \
        char* khb = reinterpret_cast<char*>(&Kh[b][0]);                             \
        char* vtb = reinterpret_cast<char*>(&Vt[b][0]);                             \
        _Pragma("unroll")                                                           \
        for (int r = 0; r < 4; ++r) {                                               \
            f16x4 k4;                                                               \
            k4[0] = (_Float16)kreg[r][0]; k4[1] = (_Float16)kreg[r][1];             \
            k4[2] = (_Float16)kreg[r][2]; k4[3] = (_Float16)kreg[r][3];             \
            *reinterpret_cast<f16x4*>(khb + kaddr(rb + r, sd)) = k4;                \
        }                                                                           \
        _Pragma("unroll")                                                           \
        for (int j = 0; j < 4; ++j) {                                               \
            f16x4 v4;                                                               \
            v4[0] = (_Float16)vreg[0][j]; v4[1] = (_Float16)vreg[1][j];             \
            v4[2] = (_Float16)vreg[2][j]; v4[3] = (_Float16)vreg[3][j];             \
            *reinterpret_cast<f16x4*>(vtb + vaddr(sd + j, kvpb)) = v4;              \
        }                                                                           \
    }

    // ---- prologue: tile 0 ----
    LOAD_TILE(0);
    STORE_TILE(0);
    __syncthreads();

    for (int kt = 0; kt < NKT; ++kt) {
        const int cur = kt & 1;
        // issue next tile's global loads; they land during compute below
        if (kt + 1 < NKT) LOAD_TILE((kt + 1) * KB);

        const char* khb = reinterpret_cast<const char*>(&Kh[cur][0]);
        const char* vtb = reinterpret_cast<const char*>(&Vt[cur][0]);

        // ---- S^T = K . Q^T : D[kv][q] (exp2 units), acc init with mask bias ----
        f32x4 st[4];
#pragma unroll
        for (int t = 0; t < 4; ++t) {
            f32x4 binit;
#pragma unroll
            for (int r = 0; r < 4; ++r) binit[r] = biasLds[cur][16 * t + 4 * hi + r];
            st[t] = binit;
        }
        __builtin_amdgcn_s_setprio(1);
#pragma unroll
        for (int t = 0; t < 4; ++t) {
#pragma unroll
            for (int c = 0; c < 4; ++c) {
                const unsigned ka = kaddr(16 * t + q16, 32 * c + 8 * hi);
                f16x8 kf = *reinterpret_cast<const f16x8*>(khb + ka);
                st[t] = __builtin_amdgcn_mfma_f32_16x16x32_f16(kf, qf[c], st[t], 0, 0, 0);
            }
        }
        __builtin_amdgcn_s_setprio(0);

        // ---- online softmax (lane-local: q = q16, kv = 16t + 4hi + r) ----
        float mx = st[0][0];
#pragma unroll
        for (int t = 0; t < 4; ++t)
#pragma unroll
            for (int r = 0; r < 4; ++r)
                mx = fmaxf(mx, st[t][r]);
        mx = fmaxf(mx, __shfl_xor(mx, 16));
        mx = fmaxf(mx, __shfl_xor(mx, 32));

        // T13 defer-max: if tile max within THR of running max (all lanes), keep
        // the old max; P bounded by 2^8 -- skips the O-rescale pass entirely.
        if (!__all(mx <= mrun + 8.0f)) {
            const float mnew = fmaxf(mrun, mx);
            const float rs   = exp2f(mrun - mnew);
            mrun = mnew;
            lrun *= rs;
            // rescale O: row q' = 4hi + r needs stat from lane (lane&48)|q'
#pragma unroll
            for (int r = 0; r < 4; ++r) {
                const int src = (lane & 48) | (4 * hi + r);
                const float rr = __shfl(rs, src);
#pragma unroll
                for (int db = 0; db < 8; ++db)
                    o[db][r] *= rr;
            }
        }

        float ps = 0.f;
        float pv[4][4];
#pragma unroll
        for (int t = 0; t < 4; ++t)
#pragma unroll
            for (int r = 0; r < 4; ++r) {
                const float e = exp2f(st[t][r] - mrun);
                pv[t][r] = e;
                ps += e;
            }
        ps += __shfl_xor(ps, 16);
        ps += __shfl_xor(ps, 32);
        lrun += ps;
        // pack P (A-operand): frag h slot i: kv = 32h + 16*(i>=4) + 4hi + (i&3)
        f16x8 pf[2];
#pragma unroll
        for (int h = 0; h < 2; ++h) {
            f16x8 f;
#pragma unroll
            for (int r = 0; r < 4; ++r) {
                f[r]     = (_Float16)pv[2 * h][r];
                f[r + 4] = (_Float16)pv[2 * h + 1][r];
            }
            pf[h] = f;
        }

        // ---- PV: o[db] += P . V ; B-frag = ONE b128 read (sigma layout) ----
        __builtin_amdgcn_s_setprio(1);
#pragma unroll
        for (int db = 0; db < 8; ++db) {
            const int d = db * 16 + q16;
            f16x8 v0 = *reinterpret_cast<const f16x8*>(vtb + vaddr(d, 8 * hi));
            f16x8 v1 = *reinterpret_cast<const f16x8*>(vtb + vaddr(d, 32 + 8 * hi));
            o[db] = __builtin_amdgcn_mfma_f32_16x16x32_f16(pf[0], v0, o[db], 0, 0, 0);
            o[db] = __builtin_amdgcn_mfma_f32_16x16x32_f16(pf[1], v1, o[db], 0, 0, 0);
        }
        __builtin_amdgcn_s_setprio(0);

        // ---- write next tile to the other buffer; single barrier per iteration ----
        if (kt + 1 < NKT) STORE_TILE(cur ^ 1);
        __syncthreads();
    }

    // ---- epilogue: normalize by l and store (rows q' = 4hi + r) ----
    float* Op = Og + ((size_t)bh * TSEQ + qbase) * DDIM;
#pragma unroll
    for (int r = 0; r < 4; ++r) {
        const int src = (lane & 48) | (4 * hi + r);
        const float inv = 1.0f / __shfl(lrun, src);
        const int qrow = 4 * hi + r;
#pragma unroll
        for (int db = 0; db < 8; ++db)
            Op[(size_t)qrow * DDIM + db * 16 + q16] = o[db][r] * inv;
    }
}

extern "C" void kernel_launch(void* const* d_in, const int* in_sizes, int n_in,
                              void* d_out, int out_size, void* d_ws, size_t ws_size,
                              hipStream_t stream) {
    const float* q = (const float*)d_in[0];
    const float* k = (const float*)d_in[1];
    const float* v = (const float*)d_in[2];
    const unsigned char* m = (const unsigned char*)d_in[3];
    float* out = (float*)d_out;
    dim3 grid(BHN, TSEQ / QB);   // (32, 16) = 512 blocks = 2 per CU
    dim3 block(512);
    attn_fwd<<<grid, block, 0, stream>>>(q, k, v, m, out);
}

// Round 12
// 212.888 us; speedup vs baseline: 1.1588x; 1.1588x over previous
//
#include <hip/hip_runtime.h>
#include <hip/hip_fp16.h>

// FullAttention fwd: BH=32, T=2048, D=128, fp32 in/out, key_padding_mask (True=masked).
// R12 = R9 structure (measured 117us) + exp2-folded scale + T13 defer-max.
// 512 thr (8 waves x 32 q = 256 q/block), grid (32,8) = 256 blocks = 1/CU.
// (R11 lesson: LDS > 64KB forbids 2 blocks/CU; QB=128@512blocks doubled staging
//  with zero occupancy gain -> regression. Stay at QB=256.)
// FP16 single-pass MFMA; double-buffered LDS (65KB), ONE barrier/iter;
// swapped QK^T => softmax lane-local; P in-register feeds PV A-operand;
// V^T sigma layout gives one b128 read per PV B-frag.

#define BHN  32
#define TSEQ 2048
#define DDIM 128
#define QB   256   // q rows per block
#define KB   64    // kv rows per tile
#define NKT  (TSEQ / KB)

typedef __attribute__((ext_vector_type(4))) float    f32x4;
typedef __attribute__((ext_vector_type(8))) _Float16 f16x8;
typedef __attribute__((ext_vector_type(4))) _Float16 f16x4;

// K byte addr (row-major [64][128] f16, m214 XOR swizzle)
__device__ __forceinline__ unsigned kaddr(int row, int d) {
    return ((unsigned)(row * 256 + d * 2)) ^ ((unsigned)(row & 7) << 4);
}
// V^T byte addr: (d, kvp) with 16B-granule XOR swizzle (preserves b64/b128 alignment)
__device__ __forceinline__ unsigned vaddr(int d, int kvp) {
    return ((unsigned)(d * 128 + kvp * 2)) ^ (((unsigned)((d ^ (d >> 3)) & 7)) << 4);
}

__global__ __launch_bounds__(512, 2)
void attn_fwd(const float* __restrict__ Qg, const float* __restrict__ Kg,
              const float* __restrict__ Vg, const unsigned char* __restrict__ Mg,
              float* __restrict__ Og)
{
    __shared__ __align__(16) unsigned short Kh[2][KB * DDIM]; // 2x16KB f16, XOR-swizzled
    __shared__ __align__(16) unsigned short Vt[2][DDIM * KB]; // 2x16KB f16 (d, sigma(kv))
    __shared__ float biasLds[2][KB];
    __shared__ int mflag;

    const int tid  = threadIdx.x;
    const int lane = tid & 63;
    const int wave = tid >> 6;
    const int q16  = lane & 15;
    const int hi   = lane >> 4;

    const int bh    = blockIdx.x;
    const int qbase = blockIdx.y * QB + wave * 32;

    // 1/sqrt(128) * log2(e): softmax computed in exp2 units
    const float scale = 0.088388347648318447f * 1.4426950408889634f;

    const float* Qp = Qg + ((size_t)bh * TSEQ + qbase) * DDIM;
    const float* Kp = Kg + (size_t)bh * TSEQ * DDIM;
    const float* Vp = Vg + (size_t)bh * TSEQ * DDIM;

    // ---- mask layout detection (probe first 2KB; valid under both layouts) ----
    if (tid == 0) mflag = 0;
    __syncthreads();
    {
        int f = 0;
#pragma unroll
        for (int j = 0; j < 4; ++j) {
            const int idx = tid * 4 + j;
            if ((idx & 3) != 0 && Mg[idx] != 0) f = 1;
        }
        if (f) atomicOr(&mflag, 1);
    }
    __syncthreads();
    const int isByte = mflag;   // block-uniform

    // ---- Q fragments (fp16): lane holds Q[16qt+q16][32c+8hi+i]*scale ----
    f16x8 qf[2][4];
#pragma unroll
    for (int qt = 0; qt < 2; ++qt) {
        const float* qrow = Qp + (size_t)(qt * 16 + q16) * DDIM;
#pragma unroll
        for (int c = 0; c < 4; ++c) {
            const int d0 = 32 * c + 8 * hi;
            f32x4 a = *reinterpret_cast<const f32x4*>(qrow + d0);
            f32x4 b = *reinterpret_cast<const f32x4*>(qrow + d0 + 4);
            f16x8 f;
#pragma unroll
            for (int i = 0; i < 8; ++i)
                f[i] = (_Float16)((i < 4 ? a[i] : b[i - 4]) * scale);
            qf[qt][c] = f;
        }
    }

    f32x4 o[2][8];
#pragma unroll
    for (int qt = 0; qt < 2; ++qt)
#pragma unroll
        for (int db = 0; db < 8; ++db)
            o[qt][db] = (f32x4){0.f, 0.f, 0.f, 0.f};
    float mrun[2] = {-1e30f, -1e30f};
    float lrun[2] = {0.f, 0.f};

    // ---- staging assignment: thread owns kv-quad rb..rb+3 at d = sd..sd+3 ----
    const int sd   = (tid & 31) * 4;
    const int qrw  = (((tid >> 5) & 1) << 2) | ((tid >> 6) & 3) | (((tid >> 8) & 1) << 3);
    const int rb   = qrw * 4;
    // sigma base of the quad: sigma(4m+r) = kvpb + r
    const int kvpb = (((qrw >> 2) & 1) << 2) | ((qrw & 3) << 3) | (((qrw >> 3) & 1) << 5);

    f32x4 kreg[4], vreg[4];
    int mreg = 0;

#define LOAD_TILE(kv0)                                                              \
    {                                                                               \
        _Pragma("unroll")                                                           \
        for (int r = 0; r < 4; ++r) {                                               \
            kreg[r] = *reinterpret_cast<const f32x4*>(Kp + (size_t)((kv0) + rb + r) * DDIM + sd); \
            vreg[r] = *reinterpret_cast<const f32x4*>(Vp + (size_t)((kv0) + rb + r) * DDIM + sd); \
        }                                                                           \
        if (tid < KB) {                                                             \
            const size_t mi = (size_t)bh * TSEQ + (kv0) + tid;                      \
            mreg = isByte ? (int)Mg[mi] : ((const int*)Mg)[mi];                     \
        }                                                                           \
    }

#define STORE_TILE(b)                                                               \
    {                                                                               \
        if (tid < KB) biasLds[b][tid] = mreg ? -1e30f : 0.0f;                       \
        char* khb = reinterpret_cast<char*>(&Kh[b][0]);                             \
        char* vtb = reinterpret_cast<char*>(&Vt[b][0]);                             \
        _Pragma("unroll")                                                           \
        for (int r = 0; r < 4; ++r) {                                               \
            f16x4 k4;                                                               \
            k4[0] = (_Float16)kreg[r][0]; k4[1] = (_Float16)kreg[r][1];             \
            k4[2] = (_Float16)kreg[r][2]; k4[3] = (_Float16)kreg[r][3];             \
            *reinterpret_cast<f16x4*>(khb + kaddr(rb + r, sd)) = k4;                \
        }                                                                           \
        _Pragma("unroll")                                                           \
        for (int j = 0; j < 4; ++j) {                                               \
            f16x4 v4;                                                               \
            v4[0] = (_Float16)vreg[0][j]; v4[1] = (_Float16)vreg[1][j];             \
            v4[2] = (_Float16)vreg[2][j]; v4[3] = (_Float16)vreg[3][j];             \
            *reinterpret_cast<f16x4*>(vtb + vaddr(sd + j, kvpb)) = v4;              \
        }                                                                           \
    }

    // ---- prologue: tile 0 ----
    LOAD_TILE(0);
    STORE_TILE(0);
    __syncthreads();

    for (int kt = 0; kt < NKT; ++kt) {
        const int cur = kt & 1;
        // issue next tile's global loads; they land during compute below
        if (kt + 1 < NKT) LOAD_TILE((kt + 1) * KB);

        const char* khb = reinterpret_cast<const char*>(&Kh[cur][0]);
        const char* vtb = reinterpret_cast<const char*>(&Vt[cur][0]);

        // ---- S^T = K . Q^T : D[kv][q] (exp2 units), acc init with mask bias ----
        f32x4 st[2][4];
#pragma unroll
        for (int t = 0; t < 4; ++t) {
            f32x4 binit;
#pragma unroll
            for (int r = 0; r < 4; ++r) binit[r] = biasLds[cur][16 * t + 4 * hi + r];
            st[0][t] = binit;
            st[1][t] = binit;
        }
        __builtin_amdgcn_s_setprio(1);
#pragma unroll
        for (int t = 0; t < 4; ++t) {
#pragma unroll
            for (int c = 0; c < 4; ++c) {
                const unsigned ka = kaddr(16 * t + q16, 32 * c + 8 * hi);
                f16x8 kf = *reinterpret_cast<const f16x8*>(khb + ka);
                st[0][t] = __builtin_amdgcn_mfma_f32_16x16x32_f16(kf, qf[0][c], st[0][t], 0, 0, 0);
                st[1][t] = __builtin_amdgcn_mfma_f32_16x16x32_f16(kf, qf[1][c], st[1][t], 0, 0, 0);
            }
        }
        __builtin_amdgcn_s_setprio(0);

        // ---- online softmax (lane-local: q = q16 in group qt, kv = 16t + 4hi + r) ----
        f16x8 pf[2][2];
#pragma unroll
        for (int qt = 0; qt < 2; ++qt) {
            float mx = st[qt][0][0];
#pragma unroll
            for (int t = 0; t < 4; ++t)
#pragma unroll
                for (int r = 0; r < 4; ++r)
                    mx = fmaxf(mx, st[qt][t][r]);
            mx = fmaxf(mx, __shfl_xor(mx, 16));
            mx = fmaxf(mx, __shfl_xor(mx, 32));

            // T13 defer-max: if tile max within THR of running max (all lanes), keep
            // old max (P bounded by 2^8) and skip the O-rescale pass entirely.
            if (!__all(mx <= mrun[qt] + 8.0f)) {
                const float mnew = fmaxf(mrun[qt], mx);
                const float rs   = exp2f(mrun[qt] - mnew);
                mrun[qt] = mnew;
                lrun[qt] *= rs;
                // rescale O: row q' = 4hi + r needs stat from lane (lane&48)|q'
#pragma unroll
                for (int r = 0; r < 4; ++r) {
                    const int src = (lane & 48) | (4 * hi + r);
                    const float rr = __shfl(rs, src);
#pragma unroll
                    for (int db = 0; db < 8; ++db)
                        o[qt][db][r] *= rr;
                }
            }

            float ps = 0.f;
            float pv[4][4];
#pragma unroll
            for (int t = 0; t < 4; ++t)
#pragma unroll
                for (int r = 0; r < 4; ++r) {
                    const float e = exp2f(st[qt][t][r] - mrun[qt]);
                    pv[t][r] = e;
                    ps += e;
                }
            ps += __shfl_xor(ps, 16);
            ps += __shfl_xor(ps, 32);
            lrun[qt] += ps;
            // pack P (A-operand): frag h slot i: kv = 32h + 16*(i>=4) + 4hi + (i&3)
#pragma unroll
            for (int h = 0; h < 2; ++h) {
                f16x8 f;
#pragma unroll
                for (int r = 0; r < 4; ++r) {
                    f[r]     = (_Float16)pv[2 * h][r];
                    f[r + 4] = (_Float16)pv[2 * h + 1][r];
                }
                pf[qt][h] = f;
            }
        }

        // ---- PV: o[qt][db] += P . V ; B-frag = ONE b128 read (sigma layout) ----
        __builtin_amdgcn_s_setprio(1);
#pragma unroll
        for (int db = 0; db < 8; ++db) {
            const int d = db * 16 + q16;
            f16x8 v0 = *reinterpret_cast<const f16x8*>(vtb + vaddr(d, 8 * hi));
            f16x8 v1 = *reinterpret_cast<const f16x8*>(vtb + vaddr(d, 32 + 8 * hi));
            o[0][db] = __builtin_amdgcn_mfma_f32_16x16x32_f16(pf[0][0], v0, o[0][db], 0, 0, 0);
            o[0][db] = __builtin_amdgcn_mfma_f32_16x16x32_f16(pf[0][1], v1, o[0][db], 0, 0, 0);
            o[1][db] = __builtin_amdgcn_mfma_f32_16x16x32_f16(pf[1][0], v0, o[1][db], 0, 0, 0);
            o[1][db] = __builtin_amdgcn_mfma_f32_16x16x32_f16(pf[1][1], v1, o[1][db], 0, 0, 0);
        }
        __builtin_amdgcn_s_setprio(0);

        // ---- write next tile to the other buffer; single barrier per iteration ----
        if (kt + 1 < NKT) STORE_TILE(cur ^ 1);
        __syncthreads();
    }

    // ---- epilogue: normalize by l and store (rows q' = 16qt + 4hi + r) ----
    float* Op = Og + ((size_t)bh * TSEQ + qbase) * DDIM;
#pragma unroll
    for (int qt = 0; qt < 2; ++qt)
#pragma unroll
        for (int r = 0; r < 4; ++r) {
            const int src = (lane & 48) | (4 * hi + r);
            const float inv = 1.0f / __shfl(lrun[qt], src);
            const int qrow = qt * 16 + 4 * hi + r;
#pragma unroll
            for (int db = 0; db < 8; ++db)
                Op[(size_t)qrow * DDIM + db * 16 + q16] = o[qt][db][r] * inv;
        }
}

extern "C" void kernel_launch(void* const* d_in, const int* in_sizes, int n_in,
                              void* d_out, int out_size, void* d_ws, size_t ws_size,
                              hipStream_t stream) {
    const float* q = (const float*)d_in[0];
    const float* k = (const float*)d_in[1];
    const float* v = (const float*)d_in[2];
    const unsigned char* m = (const unsigned char*)d_in[3];
    float* out = (float*)d_out;
    dim3 grid(BHN, TSEQ / QB);   // (32, 8) = 256 blocks = 1 per CU
    dim3 block(512);
    attn_fwd<<<grid, block, 0, stream>>>(q, k, v, m, out);
}

// Round 14
// 193.335 us; speedup vs baseline: 1.2760x; 1.1011x over previous
//
#include <hip/hip_runtime.h>
#include <hip/hip_fp16.h>

// FullAttention fwd: BH=32, T=2048, D=128, fp32 in/out, key_padding_mask (True=masked).
// R13 = R9 structure + RAW exp2 (v_exp_f32 via builtin; R12's exp2f() was the slow
// libm path -> VALU regression) + pkrtz packed f32->f16 staging/P-pack + deferred
// l-reduction (per-lane partial, epilogue reduce).
// 512 thr (8 waves x 32 q = 256 q/block), grid (32,8) = 256 blocks = 1/CU.
// FP16 single-pass MFMA; double-buffered LDS (65KB), ONE barrier/iter;
// swapped QK^T => softmax lane-local; P in-register feeds PV A-operand;
// V^T sigma layout gives one b128 read per PV B-frag. T13 defer-max (THR=8).

#define BHN  32
#define TSEQ 2048
#define DDIM 128
#define QB   256   // q rows per block
#define KB   64    // kv rows per tile
#define NKT  (TSEQ / KB)

typedef __attribute__((ext_vector_type(4))) float    f32x4;
typedef __attribute__((ext_vector_type(8))) _Float16 f16x8;
typedef __attribute__((ext_vector_type(4))) _Float16 f16x4;

// packed f32x2 -> f16x2 (RTZ), one v_cvt_pkrtz_f16_f32; returns raw 32-bit word
__device__ __forceinline__ unsigned pkrtz_u(float a, float b) {
    auto t = __builtin_amdgcn_cvt_pkrtz(a, b);
    union { decltype(t) s; unsigned u; } cv; cv.s = t; return cv.u;
}
// K byte addr (row-major [64][128] f16, m214 XOR swizzle)
__device__ __forceinline__ unsigned kaddr(int row, int d) {
    return ((unsigned)(row * 256 + d * 2)) ^ ((unsigned)(row & 7) << 4);
}
// V^T byte addr: (d, kvp) with 16B-granule XOR swizzle (preserves b64/b128 alignment)
__device__ __forceinline__ unsigned vaddr(int d, int kvp) {
    return ((unsigned)(d * 128 + kvp * 2)) ^ (((unsigned)((d ^ (d >> 3)) & 7)) << 4);
}

__global__ __launch_bounds__(512, 2)
void attn_fwd(const float* __restrict__ Qg, const float* __restrict__ Kg,
              const float* __restrict__ Vg, const unsigned char* __restrict__ Mg,
              float* __restrict__ Og)
{
    __shared__ __align__(16) unsigned short Kh[2][KB * DDIM]; // 2x16KB f16, XOR-swizzled
    __shared__ __align__(16) unsigned short Vt[2][DDIM * KB]; // 2x16KB f16 (d, sigma(kv))
    __shared__ float biasLds[2][KB];
    __shared__ int mflag;

    const int tid  = threadIdx.x;
    const int lane = tid & 63;
    const int wave = tid >> 6;
    const int q16  = lane & 15;
    const int hi   = lane >> 4;

    const int bh    = blockIdx.x;
    const int qbase = blockIdx.y * QB + wave * 32;

    // 1/sqrt(128) * log2(e): softmax computed in exp2 units
    const float scale = 0.088388347648318447f * 1.4426950408889634f;

    const float* Qp = Qg + ((size_t)bh * TSEQ + qbase) * DDIM;
    const float* Kp = Kg + (size_t)bh * TSEQ * DDIM;
    const float* Vp = Vg + (size_t)bh * TSEQ * DDIM;

    // ---- mask layout detection (probe first 2KB; valid under both layouts) ----
    if (tid == 0) mflag = 0;
    __syncthreads();
    {
        int f = 0;
#pragma unroll
        for (int j = 0; j < 4; ++j) {
            const int idx = tid * 4 + j;
            if ((idx & 3) != 0 && Mg[idx] != 0) f = 1;
        }
        if (f) atomicOr(&mflag, 1);
    }
    __syncthreads();
    const int isByte = mflag;   // block-uniform

    // ---- Q fragments (fp16): lane holds Q[16qt+q16][32c+8hi+i]*scale ----
    f16x8 qf[2][4];
#pragma unroll
    for (int qt = 0; qt < 2; ++qt) {
        const float* qrow = Qp + (size_t)(qt * 16 + q16) * DDIM;
#pragma unroll
        for (int c = 0; c < 4; ++c) {
            const int d0 = 32 * c + 8 * hi;
            f32x4 a = *reinterpret_cast<const f32x4*>(qrow + d0);
            f32x4 b = *reinterpret_cast<const f32x4*>(qrow + d0 + 4);
            f16x8 f;
#pragma unroll
            for (int i = 0; i < 8; ++i)
                f[i] = (_Float16)((i < 4 ? a[i] : b[i - 4]) * scale);
            qf[qt][c] = f;
        }
    }

    f32x4 o[2][8];
#pragma unroll
    for (int qt = 0; qt < 2; ++qt)
#pragma unroll
        for (int db = 0; db < 8; ++db)
            o[qt][db] = (f32x4){0.f, 0.f, 0.f, 0.f};
    float mrun[2] = {-1e30f, -1e30f};
    float lrun[2] = {0.f, 0.f};   // per-lane PARTIAL row-sums; reduced in epilogue

    // ---- staging assignment: thread owns kv-quad rb..rb+3 at d = sd..sd+3 ----
    const int sd   = (tid & 31) * 4;
    const int qrw  = (((tid >> 5) & 1) << 2) | ((tid >> 6) & 3) | (((tid >> 8) & 1) << 3);
    const int rb   = qrw * 4;
    // sigma base of the quad: sigma(4m+r) = kvpb + r
    const int kvpb = (((qrw >> 2) & 1) << 2) | ((qrw & 3) << 3) | (((qrw >> 3) & 1) << 5);

    f32x4 kreg[4], vreg[4];
    int mreg = 0;

#define LOAD_TILE(kv0)                                                              \
    {                                                                               \
        _Pragma("unroll")                                                           \
        for (int r = 0; r < 4; ++r) {                                               \
            kreg[r] = *reinterpret_cast<const f32x4*>(Kp + (size_t)((kv0) + rb + r) * DDIM + sd); \
            vreg[r] = *reinterpret_cast<const f32x4*>(Vp + (size_t)((kv0) + rb + r) * DDIM + sd); \
        }                                                                           \
        if (tid < KB) {                                                             \
            const size_t mi = (size_t)bh * TSEQ + (kv0) + tid;                      \
            mreg = isByte ? (int)Mg[mi] : ((const int*)Mg)[mi];                     \
        }                                                                           \
    }

#define STORE_TILE(b)                                                               \
    {                                                                               \
        if (tid < KB) biasLds[b][tid] = mreg ? -1e30f : 0.0f;                       \
        char* khb = reinterpret_cast<char*>(&Kh[b][0]);                             \
        char* vtb = reinterpret_cast<char*>(&Vt[b][0]);                             \
        _Pragma("unroll")                                                           \
        for (int r = 0; r < 4; ++r) {                                               \
            union { f16x4 v; unsigned u[2]; } k4;                                   \
            k4.u[0] = pkrtz_u(kreg[r][0], kreg[r][1]);                              \
            k4.u[1] = pkrtz_u(kreg[r][2], kreg[r][3]);                              \
            *reinterpret_cast<f16x4*>(khb + kaddr(rb + r, sd)) = k4.v;              \
        }                                                                           \
        _Pragma("unroll")                                                           \
        for (int j = 0; j < 4; ++j) {                                               \
            union { f16x4 v; unsigned u[2]; } v4;                                   \
            v4.u[0] = pkrtz_u(vreg[0][j], vreg[1][j]);                              \
            v4.u[1] = pkrtz_u(vreg[2][j], vreg[3][j]);                              \
            *reinterpret_cast<f16x4*>(vtb + vaddr(sd + j, kvpb)) = v4.v;            \
        }                                                                           \
    }

    // ---- prologue: tile 0 ----
    LOAD_TILE(0);
    STORE_TILE(0);
    __syncthreads();

    for (int kt = 0; kt < NKT; ++kt) {
        const int cur = kt & 1;
        // issue next tile's global loads; they land during compute below
        if (kt + 1 < NKT) LOAD_TILE((kt + 1) * KB);

        const char* khb = reinterpret_cast<const char*>(&Kh[cur][0]);
        const char* vtb = reinterpret_cast<const char*>(&Vt[cur][0]);

        // ---- S^T = K . Q^T : D[kv][q] (exp2 units), acc init with mask bias ----
        f32x4 st[2][4];
#pragma unroll
        for (int t = 0; t < 4; ++t) {
            f32x4 binit;
#pragma unroll
            for (int r = 0; r < 4; ++r) binit[r] = biasLds[cur][16 * t + 4 * hi + r];
            st[0][t] = binit;
            st[1][t] = binit;
        }
        __builtin_amdgcn_s_setprio(1);
#pragma unroll
        for (int t = 0; t < 4; ++t) {
#pragma unroll
            for (int c = 0; c < 4; ++c) {
                const unsigned ka = kaddr(16 * t + q16, 32 * c + 8 * hi);
                f16x8 kf = *reinterpret_cast<const f16x8*>(khb + ka);
                st[0][t] = __builtin_amdgcn_mfma_f32_16x16x32_f16(kf, qf[0][c], st[0][t], 0, 0, 0);
                st[1][t] = __builtin_amdgcn_mfma_f32_16x16x32_f16(kf, qf[1][c], st[1][t], 0, 0, 0);
            }
        }
        __builtin_amdgcn_s_setprio(0);

        // ---- online softmax (lane-local: q = q16 in group qt, kv = 16t + 4hi + r) ----
        f16x8 pf[2][2];
#pragma unroll
        for (int qt = 0; qt < 2; ++qt) {
            float mx = st[qt][0][0];
#pragma unroll
            for (int t = 0; t < 4; ++t)
#pragma unroll
                for (int r = 0; r < 4; ++r)
                    mx = fmaxf(mx, st[qt][t][r]);
            mx = fmaxf(mx, __shfl_xor(mx, 16));
            mx = fmaxf(mx, __shfl_xor(mx, 32));

            // T13 defer-max: if tile max within THR of running max (all lanes), keep
            // old max (P bounded by 2^8) and skip the O-rescale pass entirely.
            if (!__all(mx <= mrun[qt] + 8.0f)) {
                const float mnew = fmaxf(mrun[qt], mx);
                const float rs   = __builtin_amdgcn_exp2f(mrun[qt] - mnew);
                mrun[qt] = mnew;
                lrun[qt] *= rs;   // partial-sum rescale (rs uniform across q-column lanes)
                // rescale O: row q' = 4hi + r needs stat from lane (lane&48)|q'
#pragma unroll
                for (int r = 0; r < 4; ++r) {
                    const int src = (lane & 48) | (4 * hi + r);
                    const float rr = __shfl(rs, src);
#pragma unroll
                    for (int db = 0; db < 8; ++db)
                        o[qt][db][r] *= rr;
                }
            }

            float ps = 0.f;
            float pv[4][4];
#pragma unroll
            for (int t = 0; t < 4; ++t)
#pragma unroll
                for (int r = 0; r < 4; ++r) {
                    const float e = __builtin_amdgcn_exp2f(st[qt][t][r] - mrun[qt]);
                    pv[t][r] = e;
                    ps += e;
                }
            lrun[qt] += ps;   // per-lane partial; cross-lane reduce deferred to epilogue
            // pack P (A-operand): frag h slot i: kv = 32h + 16*(i>=4) + 4hi + (i&3)
#pragma unroll
            for (int h = 0; h < 2; ++h) {
                union { f16x8 v; unsigned u[4]; } f;
                f.u[0] = pkrtz_u(pv[2 * h][0], pv[2 * h][1]);
                f.u[1] = pkrtz_u(pv[2 * h][2], pv[2 * h][3]);
                f.u[2] = pkrtz_u(pv[2 * h + 1][0], pv[2 * h + 1][1]);
                f.u[3] = pkrtz_u(pv[2 * h + 1][2], pv[2 * h + 1][3]);
                pf[qt][h] = f.v;
            }
        }

        // ---- PV: o[qt][db] += P . V ; B-frag = ONE b128 read (sigma layout) ----
        __builtin_amdgcn_s_setprio(1);
#pragma unroll
        for (int db = 0; db < 8; ++db) {
            const int d = db * 16 + q16;
            f16x8 v0 = *reinterpret_cast<const f16x8*>(vtb + vaddr(d, 8 * hi));
            f16x8 v1 = *reinterpret_cast<const f16x8*>(vtb + vaddr(d, 32 + 8 * hi));
            o[0][db] = __builtin_amdgcn_mfma_f32_16x16x32_f16(pf[0][0], v0, o[0][db], 0, 0, 0);
            o[0][db] = __builtin_amdgcn_mfma_f32_16x16x32_f16(pf[0][1], v1, o[0][db], 0, 0, 0);
            o[1][db] = __builtin_amdgcn_mfma_f32_16x16x32_f16(pf[1][0], v0, o[1][db], 0, 0, 0);
            o[1][db] = __builtin_amdgcn_mfma_f32_16x16x32_f16(pf[1][1], v1, o[1][db], 0, 0, 0);
        }
        __builtin_amdgcn_s_setprio(0);

        // ---- write next tile to the other buffer; single barrier per iteration ----
        if (kt + 1 < NKT) STORE_TILE(cur ^ 1);
        __syncthreads();
    }

    // ---- epilogue: reduce l partials, normalize, store (rows q' = 16qt + 4hi + r) ----
    float* Op = Og + ((size_t)bh * TSEQ + qbase) * DDIM;
#pragma unroll
    for (int qt = 0; qt < 2; ++qt) {
        float lt = lrun[qt];
        lt += __shfl_xor(lt, 16);
        lt += __shfl_xor(lt, 32);
#pragma unroll
        for (int r = 0; r < 4; ++r) {
            const int src = (lane & 48) | (4 * hi + r);
            const float inv = 1.0f / __shfl(lt, src);
            const int qrow = qt * 16 + 4 * hi + r;
#pragma unroll
            for (int db = 0; db < 8; ++db)
                Op[(size_t)qrow * DDIM + db * 16 + q16] = o[qt][db][r] * inv;
        }
    }
}

extern "C" void kernel_launch(void* const* d_in, const int* in_sizes, int n_in,
                              void* d_out, int out_size, void* d_ws, size_t ws_size,
                              hipStream_t stream) {
    const float* q = (const float*)d_in[0];
    const float* k = (const float*)d_in[1];
    const float* v = (const float*)d_in[2];
    const unsigned char* m = (const unsigned char*)d_in[3];
    float* out = (float*)d_out;
    dim3 grid(BHN, TSEQ / QB);   // (32, 8) = 256 blocks = 1 per CU
    dim3 block(512);
    attn_fwd<<<grid, block, 0, stream>>>(q, k, v, m, out);
}